// Round 2
// baseline (588.513 us; speedup 1.0000x reference)
//
#include <hip/hip_runtime.h>
#include <hip/hip_bf16.h>

#define TQ 2048
#define TKV 2048
#define NH 16
#define HD 64
#define DM 1024
#define BSZ 4
#define LDKV 2048  // fused K|V buffer row stride (elements)

typedef __bf16 bf16_t;
typedef bf16_t bf16x8 __attribute__((ext_vector_type(8)));
typedef float f32x4 __attribute__((ext_vector_type(4)));

__device__ __forceinline__ f32x4 MFMA16(bf16x8 a, bf16x8 b, f32x4 c) {
  return __builtin_amdgcn_mfma_f32_16x16x32_bf16(a, b, c, 0, 0, 0);
}

__device__ __forceinline__ void gload_lds16(const void* g, void* l) {
  __builtin_amdgcn_global_load_lds((const __attribute__((address_space(1))) void*)g,
                                   (__attribute__((address_space(3))) void*)l,
                                   16, 0, 0);
}

// swizzled LDS index helpers (both-sides-or-neither: same helper for write & read)
// Vt logical [d][k], 64x64; bank-conflict-free for d-scatter writes and k-contig b128 reads
__device__ __forceinline__ int vt_idx(int d, int k) {
  int bb = (k >> 3) ^ ((d >> 3) & 7) ^ (d & 7);
  return d * 64 + bb * 8 + (k & 7);
}
// Pl logical [q][k], 16x64 per wave
__device__ __forceinline__ int pl_idx(int q, int k) {
  int bb = (k >> 3) ^ (q & 7);
  return q * 64 + bb * 8 + (k & 7);
}

// ---------------- fused fp32 -> bf16 conversion (8 elems/thread) -----------
__global__ __launch_bounds__(256) void cvt_all(
    const float* __restrict__ xq, const float* __restrict__ xkv,
    const float* __restrict__ wq, const float* __restrict__ wk,
    const float* __restrict__ wv, const float* __restrict__ wo,
    bf16_t* __restrict__ oxq, bf16_t* __restrict__ oxkv,
    bf16_t* __restrict__ owq, bf16_t* __restrict__ owk,
    bf16_t* __restrict__ owv, bf16_t* __restrict__ owo) {
  const int blk = blockIdx.x;
  const float* src;
  bf16_t* dst;
  int base;
  if (blk < 4096)      { src = xq;  dst = oxq;  base = blk; }
  else if (blk < 8192) { src = xkv; dst = oxkv; base = blk - 4096; }
  else if (blk < 8704) { src = wq;  dst = owq;  base = blk - 8192; }
  else if (blk < 9216) { src = wk;  dst = owk;  base = blk - 8704; }
  else if (blk < 9728) { src = wv;  dst = owv;  base = blk - 9216; }
  else                 { src = wo;  dst = owo;  base = blk - 9728; }
  const int i = base * 256 + threadIdx.x;
  const float4* p = reinterpret_cast<const float4*>(src) + 2 * (size_t)i;
  float4 a = p[0], b = p[1];
  bf16x8 o;
  o[0] = (bf16_t)a.x; o[1] = (bf16_t)a.y; o[2] = (bf16_t)a.z; o[3] = (bf16_t)a.w;
  o[4] = (bf16_t)b.x; o[5] = (bf16_t)b.y; o[6] = (bf16_t)b.z; o[7] = (bf16_t)b.w;
  reinterpret_cast<bf16x8*>(dst)[i] = o;
}

// ---------------- bt-GEMM: C[M,N] = A[M,K] * B[N,K]^T  (m97 structure) ----
// 128x128 tile, BK=32, 256 threads (4 waves, 2x2 wave grid, 4x4 frags/wave)
template <bool BF16_OUT>
__global__ __launch_bounds__(256) void gemm_bt(const bf16_t* __restrict__ A,
                                               const bf16_t* __restrict__ Bw,
                                               void* __restrict__ Cout,
                                               int M, int N, int K, float scale) {
  __shared__ __align__(16) bf16_t As[128 * 32];
  __shared__ __align__(16) bf16_t Bs[128 * 32];
  const int tid = threadIdx.x;
  const int l = tid & 63;
  const int w = tid >> 6;
  const int wr = w >> 1, wc = w & 1;
  const int l15 = l & 15, lg = l >> 4;
  const long bm = (long)blockIdx.x * 128;
  const long bn = (long)blockIdx.y * 128;

  f32x4 acc[4][4] = {};

  const int c0i = tid, c1i = 256 + tid;
  const long ar0 = (bm + (c0i >> 2)) * (long)K + (c0i & 3) * 8;
  const long ar1 = (bm + (c1i >> 2)) * (long)K + (c1i & 3) * 8;
  const long br0 = (bn + (c0i >> 2)) * (long)K + (c0i & 3) * 8;
  const long br1 = (bn + (c1i >> 2)) * (long)K + (c1i & 3) * 8;

  for (int k0 = 0; k0 < K; k0 += 32) {
    __syncthreads();
    gload_lds16(A + ar0 + k0, As + c0i * 8);
    gload_lds16(A + ar1 + k0, As + c1i * 8);
    gload_lds16(Bw + br0 + k0, Bs + c0i * 8);
    gload_lds16(Bw + br1 + k0, Bs + c1i * 8);
    __syncthreads();

    bf16x8 af[4], bfr[4];
#pragma unroll
    for (int i = 0; i < 4; ++i)
      af[i] = *reinterpret_cast<const bf16x8*>(As + (wr * 64 + i * 16 + l15) * 32 + lg * 8);
#pragma unroll
    for (int j = 0; j < 4; ++j)
      bfr[j] = *reinterpret_cast<const bf16x8*>(Bs + (wc * 64 + j * 16 + l15) * 32 + lg * 8);
#pragma unroll
    for (int i = 0; i < 4; ++i)
#pragma unroll
      for (int j = 0; j < 4; ++j)
        acc[i][j] = MFMA16(af[i], bfr[j], acc[i][j]);
  }

  // C/D layout: col = lane&15, row = (lane>>4)*4 + reg  [m89-verified]
#pragma unroll
  for (int i = 0; i < 4; ++i) {
#pragma unroll
    for (int j = 0; j < 4; ++j) {
#pragma unroll
      for (int r = 0; r < 4; ++r) {
        long rg = bm + wr * 64 + i * 16 + lg * 4 + r;
        long cg = bn + wc * 64 + j * 16 + l15;
        float v = acc[i][j][r] * scale;
        if (BF16_OUT)
          ((bf16_t*)Cout)[rg * N + cg] = (bf16_t)v;
        else
          ((float*)Cout)[rg * N + cg] = v;
      }
    }
  }
}

// ---------------- flash attention -----------------------------------------
// grid: (TQ/64, B*H). block: 256 threads = 4 waves; wave w owns q-rows
// q0 = bx*64 + w*16 .. +16.  KV tile = 64 rows. Q pre-scaled by 1/sqrt(hd).
// K,V live interleaved in KVb: row t = KVb + t*LDKV, K at col 0.., V at col 1024..
__global__ __launch_bounds__(256) void attn_fwd(const bf16_t* __restrict__ Qb,
                                                const bf16_t* __restrict__ KVb,
                                                const float* __restrict__ amask,
                                                const unsigned char* __restrict__ kpad,
                                                bf16_t* __restrict__ Ob) {
  __shared__ __align__(16) bf16_t Vt[64 * 64];     // swizzled V^T tile (8 KB)
  __shared__ __align__(16) bf16_t Pl[4][16 * 64];  // swizzled per-wave P (8 KB)
  const int tid = threadIdx.x;
  const int w = tid >> 6, l = tid & 63;
  const int l15 = l & 15, lg = l >> 4;
  const int b = blockIdx.y >> 4, h = blockIdx.y & 15;
  const int q0 = blockIdx.x * 64 + w * 16;
  const long qbase = (long)b * TQ * DM;
  const long kvbase = (long)b * TKV * LDKV;

  // hoist Q fragments (A-layout: row = l&15, k = (l>>4)*8 + j)
  const bf16_t* qp = Qb + qbase + (long)(q0 + l15) * DM + h * HD + lg * 8;
  bf16x8 qf0 = *reinterpret_cast<const bf16x8*>(qp);
  bf16x8 qf1 = *reinterpret_cast<const bf16x8*>(qp + 32);

  f32x4 o[4] = {};
  float m[4], ls[4];
#pragma unroll
  for (int r = 0; r < 4; ++r) { m[r] = -1e30f; ls[r] = 0.f; }

  // V staging assignment: thread handles rows (tid>>3) and 32+(tid>>3), dims (tid&7)*8..+8
  const int vrow = tid >> 3;
  const int dc = (tid & 7) * 8;

  for (int k0 = 0; k0 < TKV; k0 += 64) {
    __syncthreads();  // previous PV reads of Vt complete

    // stage V^T (coalesced 128B-per-8-lane global reads; <=2-way LDS write conflicts)
    const bf16_t* vsrc = KVb + kvbase + (long)(k0 + vrow) * LDKV + 1024 + h * HD + dc;
    bf16x8 va = *reinterpret_cast<const bf16x8*>(vsrc);
    bf16x8 vb = *reinterpret_cast<const bf16x8*>(vsrc + 32 * LDKV);
#pragma unroll
    for (int j = 0; j < 8; ++j) {
      Vt[vt_idx(dc + j, vrow)] = va[j];
      Vt[vt_idx(dc + j, vrow + 32)] = vb[j];
    }

    // QK^T: S (16q x 64k) = 4 C-frags, K read direct from global (L1/L2-hit)
    f32x4 c[4] = {{0.f, 0.f, 0.f, 0.f}, {0.f, 0.f, 0.f, 0.f},
                  {0.f, 0.f, 0.f, 0.f}, {0.f, 0.f, 0.f, 0.f}};
#pragma unroll
    for (int f = 0; f < 4; ++f) {
      const bf16_t* kp = KVb + kvbase + (long)(k0 + 16 * f + l15) * LDKV + h * HD + lg * 8;
      bf16x8 ka = *reinterpret_cast<const bf16x8*>(kp);
      bf16x8 kb = *reinterpret_cast<const bf16x8*>(kp + 32);
      c[f] = MFMA16(qf0, ka, c[f]);
      c[f] = MFMA16(qf1, kb, c[f]);
    }

    __syncthreads();  // Vt staged & visible

    bool kpm[4];
#pragma unroll
    for (int f = 0; f < 4; ++f) kpm[f] = kpad[b * TKV + k0 + 16 * f + l15] != 0;

    // online softmax: lane owns rows lg*4+r, cols 16f+l15
#pragma unroll
    for (int r = 0; r < 4; ++r) {
      const int qg = q0 + lg * 4 + r;
      const float* amrow = amask + (long)qg * TKV + k0;
      float s[4];
#pragma unroll
      for (int f = 0; f < 4; ++f) {
        s[f] = c[f][r] + amrow[16 * f + l15];
        if (kpm[f]) s[f] = -__builtin_inff();
      }
      float rmax = fmaxf(fmaxf(s[0], s[1]), fmaxf(s[2], s[3]));
#pragma unroll
      for (int d = 1; d < 16; d <<= 1) rmax = fmaxf(rmax, __shfl_xor(rmax, d, 64));
      const float mn = fmaxf(m[r], rmax);
      const float fac = __expf(m[r] - mn);
      float p[4], ps = 0.f;
#pragma unroll
      for (int f = 0; f < 4; ++f) { p[f] = __expf(s[f] - mn); ps += p[f]; }
#pragma unroll
      for (int d = 1; d < 16; d <<= 1) ps += __shfl_xor(ps, d, 64);
      ls[r] = ls[r] * fac + ps;
      m[r] = mn;
#pragma unroll
      for (int f = 0; f < 4; ++f) o[f][r] *= fac;
#pragma unroll
      for (int f = 0; f < 4; ++f)
        Pl[w][pl_idx(lg * 4 + r, 16 * f + l15)] = (bf16_t)p[f];
    }

    // PV: o[f] += P(16x64) * V^T(64x16f)  — P re-read own-wave (no barrier needed)
#pragma unroll
    for (int hh = 0; hh < 2; ++hh) {
      bf16x8 pf = *reinterpret_cast<const bf16x8*>(&Pl[w][pl_idx(l15, hh * 32 + lg * 8)]);
#pragma unroll
      for (int f = 0; f < 4; ++f) {
        bf16x8 vf = *reinterpret_cast<const bf16x8*>(&Vt[vt_idx(16 * f + l15, hh * 32 + lg * 8)]);
        o[f] = MFMA16(pf, vf, o[f]);
      }
    }
  }

  // epilogue: normalize, write bf16 heads-concat layout (b, t, h*64+d)
#pragma unroll
  for (int r = 0; r < 4; ++r) {
    const float inv = ls[r] > 0.f ? 1.f / ls[r] : 0.f;
    const long qg = q0 + lg * 4 + r;
    bf16_t* op = Ob + qbase + qg * DM + h * HD;
#pragma unroll
    for (int f = 0; f < 4; ++f) op[16 * f + l15] = (bf16_t)(o[f][r] * inv);
  }
}

// ---------------- launch ---------------------------------------------------
extern "C" void kernel_launch(void* const* d_in, const int* in_sizes, int n_in,
                              void* d_out, int out_size, void* d_ws, size_t ws_size,
                              hipStream_t stream) {
  const float* x_q = (const float*)d_in[0];
  const float* x_kv = (const float*)d_in[1];
  const float* amask = (const float*)d_in[2];
  const unsigned char* kpad = (const unsigned char*)d_in[3];
  const float* Wq = (const float*)d_in[4];
  const float* Wk = (const float*)d_in[5];
  const float* Wv = (const float*)d_in[6];
  const float* Wo = (const float*)d_in[7];
  float* out = (float*)d_out;

  char* ws = (char*)d_ws;
  const size_t MB = 1024ull * 1024ull;
  bf16_t* xq_b  = (bf16_t*)(ws + 0 * MB);    // 16 MB
  bf16_t* xkv_b = (bf16_t*)(ws + 16 * MB);   // 16 MB
  bf16_t* Qb    = (bf16_t*)(ws + 32 * MB);   // 16 MB
  bf16_t* KVb   = (bf16_t*)(ws + 48 * MB);   // 32 MB: [8192][2048] = K | V
  bf16_t* Ob    = (bf16_t*)(ws + 80 * MB);   // 16 MB
  bf16_t* Wq_b  = (bf16_t*)(ws + 96 * MB);   // 2 MB
  bf16_t* Wk_b  = (bf16_t*)(ws + 98 * MB);   // 2 MB  (contiguous with Wv_b:
  bf16_t* Wv_b  = (bf16_t*)(ws + 100 * MB);  // 2 MB   fused KV weight [2048][1024])
  bf16_t* Wo_b  = (bf16_t*)(ws + 102 * MB);  // ends at 104 MB

  const int NTOK = BSZ * TQ;  // 8192

  cvt_all<<<10240, 256, 0, stream>>>(x_q, x_kv, Wq, Wk, Wv, Wo,
                                     xq_b, xkv_b, Wq_b, Wk_b, Wv_b, Wo_b);

  // Q projection (1/sqrt(64)=0.125 folded in; exact in bf16)
  gemm_bt<true><<<dim3(NTOK / 128, DM / 128), 256, 0, stream>>>(
      xq_b, Wq_b, Qb, NTOK, DM, DM, 0.125f);
  // fused K|V projection: B = [Wk; Wv] (contiguous), N = 2048
  gemm_bt<true><<<dim3(NTOK / 128, LDKV / 128), 256, 0, stream>>>(
      xkv_b, Wk_b, KVb, NTOK, LDKV, DM, 1.f);

  attn_fwd<<<dim3(TQ / 64, BSZ * NH), 256, 0, stream>>>(Qb, KVb, amask, kpad, Ob);

  gemm_bt<false><<<dim3(NTOK / 128, DM / 128), 256, 0, stream>>>(
      Ob, Wo_b, out, NTOK, DM, DM, 1.f);
}